// Round 7
// baseline (54.694 us; speedup 1.0000x reference)
//
#include <hip/hip_runtime.h>

// Problem constants (from reference setup_inputs): B=4, N=4096, D=128.
constexpr int BATCH = 4;
constexpr int N = 4096;
constexpr int D = 128;
constexpr int J4 = N / 4;             // 1024 float4s per output row
constexpr int ROWS_PER_BLOCK = 32;    // rows of out per block (share one batch)

typedef float vfloat4 __attribute__((ext_vector_type(4)));

__device__ __forceinline__ float dot4(const vfloat4 a, const vfloat4 b) {
    return a.x * b.x + a.y * b.y + a.z * b.z + a.w * b.w;
}

// ---------------------------------------------------------------------------
// Kernel 1: per-row dual dot products (v3, unchanged from R6).
// Wave handles 4 rows via 16-lane groups; two coalesced float4 loads/lane;
// 4-step butterfly reduce within 16 lanes.
// ---------------------------------------------------------------------------
__global__ __launch_bounds__(256)
void dots_kernel(const float* __restrict__ E,
                 const float* __restrict__ W,
                 float* __restrict__ A,
                 float* __restrict__ Bv) {
    const int gtid = blockIdx.x * blockDim.x + threadIdx.x;
    const int wave = gtid >> 6;          // 0..4095
    const int g    = (threadIdx.x >> 4) & 3;
    const int s    = threadIdx.x & 15;
    const int row  = wave * 4 + g;       // exact fit: 4096*4 = 16384 rows

    const float* rp = E + (size_t)row * D;
    const vfloat4 e1 = *reinterpret_cast<const vfloat4*>(rp + s * 4);
    const vfloat4 e2 = *reinterpret_cast<const vfloat4*>(rp + 64 + s * 4);

    const vfloat4 wi1 = *reinterpret_cast<const vfloat4*>(W + s * 4);
    const vfloat4 wi2 = *reinterpret_cast<const vfloat4*>(W + 64 + s * 4);
    const vfloat4 wj1 = *reinterpret_cast<const vfloat4*>(W + D + s * 4);
    const vfloat4 wj2 = *reinterpret_cast<const vfloat4*>(W + D + 64 + s * 4);

    float pa = dot4(e1, wi1) + dot4(e2, wi2);
    float pb = dot4(e1, wj1) + dot4(e2, wj2);

    #pragma unroll
    for (int off = 8; off >= 1; off >>= 1) {
        pa += __shfl_xor(pa, off);
        pb += __shfl_xor(pb, off);
    }
    if (s == 0) {
        A[row]  = pa;
        Bv[row] = pb;
    }
}

// ---------------------------------------------------------------------------
// Kernel 2: outer-sum materialization (write-bound, 268 MB).
//   out[row][j] = A[row] + Bv[(row>>12)*N + j]
// RPB=32 this round (A/B vs 8): each Bv float4 loaded once per thread and
// reused for 32 row-stores -> Bv L2 re-reads 32MB -> 8MB; 512 blocks (2/CU).
// Plain stores (R4 A/B: plain beats nontemporal on gfx950).
// ---------------------------------------------------------------------------
__global__ __launch_bounds__(256)
void outer_kernel(const float* __restrict__ A,
                  const float* __restrict__ Bv,
                  vfloat4* __restrict__ out) {
    const int row0  = blockIdx.x * ROWS_PER_BLOCK;
    const int batch = row0 >> 12;                       // row / 4096
    const vfloat4* __restrict__ bv4 =
        reinterpret_cast<const vfloat4*>(Bv) + (size_t)batch * J4;

    float a[ROWS_PER_BLOCK];
    #pragma unroll
    for (int r = 0; r < ROWS_PER_BLOCK; ++r) a[r] = A[row0 + r];

    #pragma unroll
    for (int k = 0; k < J4 / 256; ++k) {                // 4 iterations
        const int j4 = threadIdx.x + k * 256;
        const vfloat4 b4 = bv4[j4];
        #pragma unroll
        for (int r = 0; r < ROWS_PER_BLOCK; ++r) {
            out[(size_t)(row0 + r) * J4 + j4] = b4 + a[r];
        }
    }
}

extern "C" void kernel_launch(void* const* d_in, const int* in_sizes, int n_in,
                              void* d_out, int out_size, void* d_ws, size_t ws_size,
                              hipStream_t stream) {
    const float* E = (const float*)d_in[0];   // (4, 4096, 128) f32
    const float* W = (const float*)d_in[1];   // (1, 256) f32

    // workspace: A (16384 f32) then Bv (16384 f32) = 128 KB
    float* A  = (float*)d_ws;
    float* Bv = A + (size_t)BATCH * N;

    // Kernel 1: 16384 rows, 4 rows/wave, 16 rows/block -> 1024 blocks
    {
        const int threads = 256;
        const int blocks = (BATCH * N) / 16;   // 1024
        dots_kernel<<<blocks, threads, 0, stream>>>(E, W, A, Bv);
    }

    // Kernel 2: 16384 rows / 32 rows-per-block = 512 blocks (2 per CU)
    {
        const int threads = 256;
        const int blocks = (BATCH * N) / ROWS_PER_BLOCK;   // 512
        outer_kernel<<<blocks, threads, 0, stream>>>(A, Bv, (vfloat4*)d_out);
    }
}